// Round 1
// baseline (718.057 us; speedup 1.0000x reference)
//
#include <hip/hip_runtime.h>

#define NNODES 50000
#define NEDGES 800000
#define HIDDIM 256

constexpr float NEG = 0.2f;

__device__ __forceinline__ float lrelu(float v){ return v >= 0.f ? v : NEG*v; }

// ---------------- CSR build (by dst, self-loops included) ----------------
__global__ void k_init_counts(int* counts, int n){
  int i = blockIdx.x*blockDim.x + threadIdx.x;
  if (i < n) counts[i] = 1;               // one self-loop per node
}
__global__ void k_count(const int* __restrict__ ei, int* counts, int E){
  int e = blockIdx.x*blockDim.x + threadIdx.x;
  if (e < E) atomicAdd(&counts[ei[E + e]], 1);   // dst row of edge_index
}
// single-block exclusive scan of counts -> offs (and cursor copy)
__global__ void k_scan(const int* __restrict__ counts, int* __restrict__ offs,
                       int* __restrict__ cursor, int n){
  __shared__ int sums[256];
  const int t = threadIdx.x;
  const int chunk = (n + 255)/256;
  const int lo = t*chunk, hi = min(n, lo+chunk);
  int s = 0;
  for (int i = lo; i < hi; ++i) s += counts[i];
  sums[t] = s;
  __syncthreads();
  if (t == 0){
    int run = 0;
    for (int i = 0; i < 256; ++i){ int v = sums[i]; sums[i] = run; run += v; }
    offs[n] = run;                         // total = NEDGES + NNODES
  }
  __syncthreads();
  int run = sums[t];
  for (int i = lo; i < hi; ++i){ offs[i] = run; cursor[i] = run; run += counts[i]; }
}
__global__ void k_scatter(const int* __restrict__ ei, int* cursor,
                          int* __restrict__ esrc, int E, int n){
  int e = blockIdx.x*blockDim.x + threadIdx.x;
  if (e < E){
    int s = ei[e], d = ei[E+e];
    esrc[atomicAdd(&cursor[d], 1)] = s;
  } else if (e < E + n){
    int i = e - E;
    esrc[atomicAdd(&cursor[i], 1)] = i;    // self loop
  }
}

// ---------------- GEMM (N fixed = 256) + fused alpha logits ----------------
// block: 256 threads, 8 nodes per block; thread t owns output column t.
template<int K, int NH>
__global__ __launch_bounds__(256) void k_gemm_alpha(
    const float* __restrict__ X, const float* __restrict__ W,
    const float* __restrict__ aS, const float* __restrict__ aD,
    float* __restrict__ Hout, float* __restrict__ as_o, float* __restrict__ ad_o, int n)
{
  constexpr int NPB = 8;
  __shared__ __align__(16) float xs[NPB][K];
  __shared__ float rs[NPB][4], rd[NPB][4];
  const int tid = threadIdx.x;
  const int node0 = blockIdx.x * NPB;
  const float* xb = X + (size_t)node0 * K;
  for (int i = tid; i < NPB*K; i += 256) xs[i / K][i % K] = xb[i];
  __syncthreads();

  const int col = tid;
  float acc[NPB] = {};
  for (int k = 0; k < K; k += 4){
    const float w0 = W[(k+0)*HIDDIM + col];
    const float w1 = W[(k+1)*HIDDIM + col];
    const float w2 = W[(k+2)*HIDDIM + col];
    const float w3 = W[(k+3)*HIDDIM + col];
    #pragma unroll
    for (int i = 0; i < NPB; ++i){
      const float4 xv = *reinterpret_cast<const float4*>(&xs[i][k]);
      acc[i] = fmaf(xv.x, w0, acc[i]);
      acc[i] = fmaf(xv.y, w1, acc[i]);
      acc[i] = fmaf(xv.z, w2, acc[i]);
      acc[i] = fmaf(xv.w, w3, acc[i]);
    }
  }
  #pragma unroll
  for (int i = 0; i < NPB; ++i)
    Hout[(size_t)(node0+i)*HIDDIM + col] = acc[i];

  // fused attention logits: alpha_src[n,h] = sum_c h[n,h,c]*a_src[h,c]
  const float asv = aS[col], adv = aD[col];
  const int lane = tid & 63, wv = tid >> 6;   // one wave == one head (NH==4)
  #pragma unroll
  for (int i = 0; i < NPB; ++i){
    float s1 = acc[i]*asv, s2 = acc[i]*adv;
    for (int off = 32; off; off >>= 1){
      s1 += __shfl_xor(s1, off);
      s2 += __shfl_xor(s2, off);
    }
    if (NH == 4){
      if (lane == 0){ as_o[(node0+i)*4 + wv] = s1; ad_o[(node0+i)*4 + wv] = s2; }
    } else {
      if (lane == 0){ rs[i][wv] = s1; rd[i][wv] = s2; }
    }
  }
  if (NH == 1){
    __syncthreads();
    if (tid < NPB){
      float a = 0.f, b = 0.f;
      #pragma unroll
      for (int w = 0; w < 4; ++w){ a += rs[tid][w]; b += rd[tid][w]; }
      as_o[node0+tid] = a; ad_o[node0+tid] = b;
    }
  }
}

// ---------------- attention softmax + aggregate; one wave per dst node ----------------
template<int NH, bool DO_ELU>
__global__ __launch_bounds__(256) void k_agg(
    const float* __restrict__ Hs,
    const float* __restrict__ as_, const float* __restrict__ ad_,
    const int* __restrict__ offs, const int* __restrict__ esrc,
    const float* __restrict__ bias, float* __restrict__ Out, int n)
{
  const int lane = threadIdx.x & 63;
  const int node = blockIdx.x*4 + (threadIdx.x >> 6);
  if (node >= n) return;
  const int start = offs[node], end = offs[node+1];

  float adv[NH], m[NH], dsum[NH];
  #pragma unroll
  for (int h = 0; h < NH; ++h){ adv[h] = ad_[node*NH + h]; m[h] = -1e30f; dsum[h] = 0.f; }

  // pass 1: per-head max over incoming edges
  for (int e = start + lane; e < end; e += 64){
    const int s = esrc[e];
    #pragma unroll
    for (int h = 0; h < NH; ++h){
      const float v = lrelu(as_[s*NH + h] + adv[h]);
      m[h] = fmaxf(m[h], v);
    }
  }
  #pragma unroll
  for (int h = 0; h < NH; ++h)
    for (int off = 32; off; off >>= 1) m[h] = fmaxf(m[h], __shfl_xor(m[h], off));

  // pass 2: denominator
  for (int e = start + lane; e < end; e += 64){
    const int s = esrc[e];
    #pragma unroll
    for (int h = 0; h < NH; ++h){
      const float v = lrelu(as_[s*NH + h] + adv[h]);
      dsum[h] += __expf(v - m[h]);
    }
  }
  #pragma unroll
  for (int h = 0; h < NH; ++h)
    for (int off = 32; off; off >>= 1) dsum[h] += __shfl_xor(dsum[h], off);

  // pass 3: weighted aggregate; lane owns channels [4*lane, 4*lane+4)
  const int head = (NH == 4) ? (lane >> 4) : 0;
  float mh, adh, rdh;
  if (NH == 4){
    mh  = (head & 2) ? ((head & 1) ? m[3]   : m[2])   : ((head & 1) ? m[1]   : m[0]);
    adh = (head & 2) ? ((head & 1) ? adv[3] : adv[2]) : ((head & 1) ? adv[1] : adv[0]);
    const float ds = (head & 2) ? ((head & 1) ? dsum[3] : dsum[2]) : ((head & 1) ? dsum[1] : dsum[0]);
    rdh = 1.f/(ds + 1e-16f);
  } else {
    mh = m[0]; adh = adv[0]; rdh = 1.f/(dsum[0] + 1e-16f);
  }

  float4 acc = {0.f, 0.f, 0.f, 0.f};
  for (int e = start; e < end; ++e){
    const int s = esrc[e];                                  // wave-uniform
    const float av = as_[s*NH + head];
    const float p = __expf(lrelu(av + adh) - mh) * rdh;
    const float4 hv = *reinterpret_cast<const float4*>(Hs + (size_t)s*HIDDIM + 4*lane);
    acc.x = fmaf(p, hv.x, acc.x);
    acc.y = fmaf(p, hv.y, acc.y);
    acc.z = fmaf(p, hv.z, acc.z);
    acc.w = fmaf(p, hv.w, acc.w);
  }
  const float4 bv = *reinterpret_cast<const float4*>(bias + 4*lane);
  acc.x += bv.x; acc.y += bv.y; acc.z += bv.z; acc.w += bv.w;
  if (DO_ELU){
    acc.x = acc.x > 0.f ? acc.x : __expf(acc.x) - 1.f;
    acc.y = acc.y > 0.f ? acc.y : __expf(acc.y) - 1.f;
    acc.z = acc.z > 0.f ? acc.z : __expf(acc.z) - 1.f;
    acc.w = acc.w > 0.f ? acc.w : __expf(acc.w) - 1.f;
  }
  *reinterpret_cast<float4*>(Out + (size_t)node*HIDDIM + 4*lane) = acc;
}

// ---------------- launch ----------------
extern "C" void kernel_launch(void* const* d_in, const int* in_sizes, int n_in,
                              void* d_out, int out_size, void* d_ws, size_t ws_size,
                              hipStream_t stream)
{
  const float* x    = (const float*)d_in[0];
  const int*   ei   = (const int*)  d_in[1];
  const float* W1   = (const float*)d_in[2];
  const float* aS1  = (const float*)d_in[3];
  const float* aD1  = (const float*)d_in[4];
  const float* b1   = (const float*)d_in[5];
  const float* W2   = (const float*)d_in[6];
  const float* aS2  = (const float*)d_in[7];
  const float* aD2  = (const float*)d_in[8];
  const float* b2   = (const float*)d_in[9];
  float* out = (float*)d_out;

  char* ws = (char*)d_ws;
  size_t off = 0;
  auto alloc = [&](size_t bytes){ void* p = ws + off; off += (bytes + 255) & ~255ull; return p; };
  float* hbuf   = (float*)alloc((size_t)NNODES*HIDDIM*sizeof(float)); // 51.2 MB
  float* as1    = (float*)alloc((size_t)NNODES*4*sizeof(float));
  float* ad1    = (float*)alloc((size_t)NNODES*4*sizeof(float));
  float* as2    = (float*)alloc((size_t)NNODES*sizeof(float));
  float* ad2    = (float*)alloc((size_t)NNODES*sizeof(float));
  int*   counts = (int*)alloc((size_t)NNODES*sizeof(int));
  int*   offs   = (int*)alloc((size_t)(NNODES+1)*sizeof(int));
  int*   cursor = (int*)alloc((size_t)NNODES*sizeof(int));
  int*   esrc   = (int*)alloc((size_t)(NEDGES+NNODES)*sizeof(int));

  // CSR by dst (rebuilt every call; deterministic up to fp-sum order)
  k_init_counts<<<(NNODES+255)/256, 256, 0, stream>>>(counts, NNODES);
  k_count     <<<(NEDGES+255)/256, 256, 0, stream>>>(ei, counts, NEDGES);
  k_scan      <<<1, 256, 0, stream>>>(counts, offs, cursor, NNODES);
  k_scatter   <<<(NEDGES+NNODES+255)/256, 256, 0, stream>>>(ei, cursor, esrc, NEDGES, NNODES);

  // layer 1: h1 = x@W1 (+ logits), then segment-softmax aggregate + b1 + ELU -> d_out
  k_gemm_alpha<128,4><<<NNODES/8, 256, 0, stream>>>(x, W1, aS1, aD1, hbuf, as1, ad1, NNODES);
  k_agg<4,true><<<(NNODES+3)/4, 256, 0, stream>>>(hbuf, as1, ad1, offs, esrc, b1, out, NNODES);

  // layer 2: g = h1e@W2 (+ logits), aggregate + b2 -> d_out
  k_gemm_alpha<256,1><<<NNODES/8, 256, 0, stream>>>(out, W2, aS2, aD2, hbuf, as2, ad2, NNODES);
  k_agg<1,false><<<(NNODES+3)/4, 256, 0, stream>>>(hbuf, as2, ad2, offs, esrc, b2, out, NNODES);
}

// Round 2
// 555.735 us; speedup vs baseline: 1.2921x; 1.2921x over previous
//
#include <hip/hip_runtime.h>

#define NNODES 50000
#define NEDGES 800000
#define HIDDIM 256

constexpr float NEG = 0.2f;

typedef __attribute__((ext_vector_type(8))) short short8_t;   // bf16x8 MFMA frag
typedef __attribute__((ext_vector_type(4))) float floatx4;    // f32x4 acc

__device__ __forceinline__ float lrelu(float v){ return v >= 0.f ? v : NEG*v; }

__device__ __forceinline__ unsigned short bf16_rn(float x){
  unsigned u = __float_as_uint(x);
  return (unsigned short)((u + 0x7FFFu + ((u >> 16) & 1u)) >> 16);
}

// ---------------- CSR build (by dst, self-loops included) ----------------
__global__ void k_init_counts(int* counts, int n){
  int i = blockIdx.x*blockDim.x + threadIdx.x;
  if (i < n) counts[i] = 1;               // one self-loop per node
}
__global__ void k_count(const int* __restrict__ ei, int* counts, int E){
  int e = blockIdx.x*blockDim.x + threadIdx.x;
  if (e < E) atomicAdd(&counts[ei[E + e]], 1);   // dst row of edge_index
}
__global__ void k_scan(const int* __restrict__ counts, int* __restrict__ offs,
                       int* __restrict__ cursor, int n){
  __shared__ int sums[256];
  const int t = threadIdx.x;
  const int chunk = (n + 255)/256;
  const int lo = t*chunk, hi = min(n, lo+chunk);
  int s = 0;
  for (int i = lo; i < hi; ++i) s += counts[i];
  sums[t] = s;
  __syncthreads();
  if (t == 0){
    int run = 0;
    for (int i = 0; i < 256; ++i){ int v = sums[i]; sums[i] = run; run += v; }
    offs[n] = run;
  }
  __syncthreads();
  int run = sums[t];
  for (int i = lo; i < hi; ++i){ offs[i] = run; cursor[i] = run; run += counts[i]; }
}
__global__ void k_scatter(const int* __restrict__ ei, int* cursor,
                          int* __restrict__ esrc, int E, int n){
  int e = blockIdx.x*blockDim.x + threadIdx.x;
  if (e < E){
    int s = ei[e], d = ei[E+e];
    esrc[atomicAdd(&cursor[d], 1)] = s;
  } else if (e < E + n){
    int i = e - E;
    esrc[atomicAdd(&cursor[i], 1)] = i;    // self loop
  }
}

// ---------------- W split: fp32 -> bf16 hi/lo, fragment-permuted layout ----
// element (k,n) -> ((k/8)*256 + n)*8 + (k%8)  so a B-frag load is 16B/lane coalesced
__global__ void k_splitW(const float* __restrict__ W, unsigned short* __restrict__ hi,
                         unsigned short* __restrict__ lo, int K){
  int idx = blockIdx.x*256 + threadIdx.x;
  if (idx >= K*HIDDIM) return;
  int k = idx / HIDDIM, n = idx % HIDDIM;
  float w = W[idx];
  unsigned short h = bf16_rn(w);
  float hf = __uint_as_float((unsigned)h << 16);
  unsigned short l = bf16_rn(w - hf);
  int p = ((k >> 3)*HIDDIM + n)*8 + (k & 7);
  hi[p] = h; lo[p] = l;
}

// ---------------- MFMA GEMM: [M,K]fp32 @ [K,256] -> [M,256]fp32 ------------
// BM=64, BN=256 (full N), 4 waves; wave w owns cols [64w,64w+64).
// split-bf16: D += Ahi*Bhi + Ahi*Blo + Alo*Bhi  (lo*lo dropped, ~2^-18 rel)
template<int K>
__global__ __launch_bounds__(256) void k_gemm_mfma(
    const float* __restrict__ A,
    const unsigned short* __restrict__ Bhi, const unsigned short* __restrict__ Blo,
    float* __restrict__ Hout, int M)
{
  constexpr int LDSK = K + 8;   // +8 shorts pad -> 2-way (free) bank alias on ds_read_b128
  __shared__ unsigned short sAhi[64*LDSK];
  __shared__ unsigned short sAlo[64*LDSK];
  const int tid = threadIdx.x;
  const int row0 = blockIdx.x*64;

  // stage A tile (64 x K fp32), split to bf16 hi/lo on the fly
  constexpr int CH = 64*K/4/256;             // float4 chunks per thread
  #pragma unroll
  for (int c = 0; c < CH; ++c){
    const int chunk = c*256 + tid;
    const int r = chunk/(K/4), ko = (chunk%(K/4))*4;
    const int gr = min(row0 + r, M-1);       // clamp tail (stores are guarded)
    const float4 v = *reinterpret_cast<const float4*>(A + (size_t)gr*K + ko);
    ushort4 h, l;
    h.x = bf16_rn(v.x); l.x = bf16_rn(v.x - __uint_as_float((unsigned)h.x<<16));
    h.y = bf16_rn(v.y); l.y = bf16_rn(v.y - __uint_as_float((unsigned)h.y<<16));
    h.z = bf16_rn(v.z); l.z = bf16_rn(v.z - __uint_as_float((unsigned)h.z<<16));
    h.w = bf16_rn(v.w); l.w = bf16_rn(v.w - __uint_as_float((unsigned)h.w<<16));
    *reinterpret_cast<ushort4*>(&sAhi[r*LDSK + ko]) = h;
    *reinterpret_cast<ushort4*>(&sAlo[r*LDSK + ko]) = l;
  }
  __syncthreads();

  const int w = tid >> 6, l = tid & 63;
  const int lr = l & 15, lg = l >> 4;        // frag non-K index, k-group
  const int n0 = w*64;
  floatx4 acc[4][4] = {};

  for (int ks = 0; ks < K/32; ++ks){
    short8_t ah[4], al[4], bh[4], bl[4];
    #pragma unroll
    for (int m = 0; m < 4; ++m){
      const int off = (16*m + lr)*LDSK + ks*32 + lg*8;
      ah[m] = *reinterpret_cast<const short8_t*>(&sAhi[off]);
      al[m] = *reinterpret_cast<const short8_t*>(&sAlo[off]);
    }
    #pragma unroll
    for (int n = 0; n < 4; ++n){
      const int boff = (((ks*4 + lg)*HIDDIM) + n0 + 16*n + lr)*8;
      bh[n] = *reinterpret_cast<const short8_t*>(&Bhi[boff]);
      bl[n] = *reinterpret_cast<const short8_t*>(&Blo[boff]);
    }
    #pragma unroll
    for (int m = 0; m < 4; ++m)
      #pragma unroll
      for (int n = 0; n < 4; ++n){
        acc[m][n] = __builtin_amdgcn_mfma_f32_16x16x32_bf16(ah[m], bh[n], acc[m][n], 0,0,0);
        acc[m][n] = __builtin_amdgcn_mfma_f32_16x16x32_bf16(ah[m], bl[n], acc[m][n], 0,0,0);
        acc[m][n] = __builtin_amdgcn_mfma_f32_16x16x32_bf16(al[m], bh[n], acc[m][n], 0,0,0);
      }
  }

  // D layout: col = lane&15, row = 4*(lane>>4)+reg  [m89-verified]
  #pragma unroll
  for (int m = 0; m < 4; ++m){
    #pragma unroll
    for (int r = 0; r < 4; ++r){
      const int row = row0 + 16*m + lg*4 + r;
      if (row < M){
        #pragma unroll
        for (int n = 0; n < 4; ++n)
          Hout[(size_t)row*HIDDIM + n0 + 16*n + lr] = acc[m][n][r];
      }
    }
  }
}

// ---------------- attention logits: as/ad[n,h] = sum_c h[n,h,c]*a[h,c] ------
template<int NH>
__global__ __launch_bounds__(256) void k_logits(
    const float* __restrict__ H, const float* __restrict__ aS, const float* __restrict__ aD,
    float* __restrict__ as_o, float* __restrict__ ad_o, int n)
{
  const int lane = threadIdx.x & 63;
  const int node = blockIdx.x*4 + (threadIdx.x >> 6);
  if (node >= n) return;
  const float4 hv = *reinterpret_cast<const float4*>(H + (size_t)node*HIDDIM + 4*lane);
  const float4 s  = *reinterpret_cast<const float4*>(aS + 4*lane);
  const float4 d  = *reinterpret_cast<const float4*>(aD + 4*lane);
  float ps = hv.x*s.x + hv.y*s.y + hv.z*s.z + hv.w*s.w;
  float pd = hv.x*d.x + hv.y*d.y + hv.z*d.z + hv.w*d.w;
  if (NH == 4){
    for (int off = 8; off; off >>= 1){ ps += __shfl_xor(ps, off); pd += __shfl_xor(pd, off); }
    if ((lane & 15) == 0){ as_o[node*4 + (lane>>4)] = ps; ad_o[node*4 + (lane>>4)] = pd; }
  } else {
    for (int off = 32; off; off >>= 1){ ps += __shfl_xor(ps, off); pd += __shfl_xor(pd, off); }
    if (lane == 0){ as_o[node] = ps; ad_o[node] = pd; }
  }
}

// ---------------- attention softmax + aggregate; one wave per dst node ------
template<int NH, bool DO_ELU>
__global__ __launch_bounds__(256) void k_agg(
    const float* __restrict__ Hs,
    const float* __restrict__ as_, const float* __restrict__ ad_,
    const int* __restrict__ offs, const int* __restrict__ esrc,
    const float* __restrict__ bias, float* __restrict__ Out, int n)
{
  const int lane = threadIdx.x & 63;
  const int node = blockIdx.x*4 + (threadIdx.x >> 6);
  if (node >= n) return;
  const int start = offs[node], end = offs[node+1];

  float adv[NH], m[NH], dsum[NH];
  #pragma unroll
  for (int h = 0; h < NH; ++h){ adv[h] = ad_[node*NH + h]; m[h] = -1e30f; dsum[h] = 0.f; }

  for (int e = start + lane; e < end; e += 64){
    const int s = esrc[e];
    #pragma unroll
    for (int h = 0; h < NH; ++h){
      const float v = lrelu(as_[s*NH + h] + adv[h]);
      m[h] = fmaxf(m[h], v);
    }
  }
  #pragma unroll
  for (int h = 0; h < NH; ++h)
    for (int off = 32; off; off >>= 1) m[h] = fmaxf(m[h], __shfl_xor(m[h], off));

  for (int e = start + lane; e < end; e += 64){
    const int s = esrc[e];
    #pragma unroll
    for (int h = 0; h < NH; ++h){
      const float v = lrelu(as_[s*NH + h] + adv[h]);
      dsum[h] += __expf(v - m[h]);
    }
  }
  #pragma unroll
  for (int h = 0; h < NH; ++h)
    for (int off = 32; off; off >>= 1) dsum[h] += __shfl_xor(dsum[h], off);

  const int head = (NH == 4) ? (lane >> 4) : 0;
  float mh, adh, rdh;
  if (NH == 4){
    mh  = (head & 2) ? ((head & 1) ? m[3]   : m[2])   : ((head & 1) ? m[1]   : m[0]);
    adh = (head & 2) ? ((head & 1) ? adv[3] : adv[2]) : ((head & 1) ? adv[1] : adv[0]);
    const float ds = (head & 2) ? ((head & 1) ? dsum[3] : dsum[2]) : ((head & 1) ? dsum[1] : dsum[0]);
    rdh = 1.f/(ds + 1e-16f);
  } else {
    mh = m[0]; adh = adv[0]; rdh = 1.f/(dsum[0] + 1e-16f);
  }

  float4 acc = {0.f, 0.f, 0.f, 0.f};
  for (int e = start; e < end; ++e){
    const int s = esrc[e];
    const float av = as_[s*NH + head];
    const float p = __expf(lrelu(av + adh) - mh) * rdh;
    const float4 hv = *reinterpret_cast<const float4*>(Hs + (size_t)s*HIDDIM + 4*lane);
    acc.x = fmaf(p, hv.x, acc.x);
    acc.y = fmaf(p, hv.y, acc.y);
    acc.z = fmaf(p, hv.z, acc.z);
    acc.w = fmaf(p, hv.w, acc.w);
  }
  const float4 bv = *reinterpret_cast<const float4*>(bias + 4*lane);
  acc.x += bv.x; acc.y += bv.y; acc.z += bv.z; acc.w += bv.w;
  if (DO_ELU){
    acc.x = acc.x > 0.f ? acc.x : __expf(acc.x) - 1.f;
    acc.y = acc.y > 0.f ? acc.y : __expf(acc.y) - 1.f;
    acc.z = acc.z > 0.f ? acc.z : __expf(acc.z) - 1.f;
    acc.w = acc.w > 0.f ? acc.w : __expf(acc.w) - 1.f;
  }
  *reinterpret_cast<float4*>(Out + (size_t)node*HIDDIM + 4*lane) = acc;
}

// ---------------- launch ----------------
extern "C" void kernel_launch(void* const* d_in, const int* in_sizes, int n_in,
                              void* d_out, int out_size, void* d_ws, size_t ws_size,
                              hipStream_t stream)
{
  const float* x    = (const float*)d_in[0];
  const int*   ei   = (const int*)  d_in[1];
  const float* W1   = (const float*)d_in[2];
  const float* aS1  = (const float*)d_in[3];
  const float* aD1  = (const float*)d_in[4];
  const float* b1   = (const float*)d_in[5];
  const float* W2   = (const float*)d_in[6];
  const float* aS2  = (const float*)d_in[7];
  const float* aD2  = (const float*)d_in[8];
  const float* b2   = (const float*)d_in[9];
  float* out = (float*)d_out;

  char* ws = (char*)d_ws;
  size_t off = 0;
  auto alloc = [&](size_t bytes){ void* p = ws + off; off += (bytes + 255) & ~255ull; return p; };
  float* hbuf   = (float*)alloc((size_t)NNODES*HIDDIM*sizeof(float)); // 51.2 MB
  float* as1    = (float*)alloc((size_t)NNODES*4*sizeof(float));
  float* ad1    = (float*)alloc((size_t)NNODES*4*sizeof(float));
  float* as2    = (float*)alloc((size_t)NNODES*sizeof(float));
  float* ad2    = (float*)alloc((size_t)NNODES*sizeof(float));
  unsigned short* W1hi = (unsigned short*)alloc((size_t)128*HIDDIM*sizeof(short));
  unsigned short* W1lo = (unsigned short*)alloc((size_t)128*HIDDIM*sizeof(short));
  unsigned short* W2hi = (unsigned short*)alloc((size_t)256*HIDDIM*sizeof(short));
  unsigned short* W2lo = (unsigned short*)alloc((size_t)256*HIDDIM*sizeof(short));
  int*   counts = (int*)alloc((size_t)NNODES*sizeof(int));
  int*   offs   = (int*)alloc((size_t)(NNODES+1)*sizeof(int));
  int*   cursor = (int*)alloc((size_t)NNODES*sizeof(int));
  int*   esrc   = (int*)alloc((size_t)(NEDGES+NNODES)*sizeof(int));

  // CSR by dst
  k_init_counts<<<(NNODES+255)/256, 256, 0, stream>>>(counts, NNODES);
  k_count     <<<(NEDGES+255)/256, 256, 0, stream>>>(ei, counts, NEDGES);
  k_scan      <<<1, 256, 0, stream>>>(counts, offs, cursor, NNODES);
  k_scatter   <<<(NEDGES+NNODES+255)/256, 256, 0, stream>>>(ei, cursor, esrc, NEDGES, NNODES);

  // weight splits (bf16 hi/lo, permuted for coalesced B-frag loads)
  k_splitW<<<(128*HIDDIM+255)/256, 256, 0, stream>>>(W1, W1hi, W1lo, 128);
  k_splitW<<<(256*HIDDIM+255)/256, 256, 0, stream>>>(W2, W2hi, W2lo, 256);

  const int gemm_grid = (NNODES + 63)/64;   // 782

  // layer 1
  k_gemm_mfma<128><<<gemm_grid, 256, 0, stream>>>(x, W1hi, W1lo, hbuf, NNODES);
  k_logits<4><<<(NNODES+3)/4, 256, 0, stream>>>(hbuf, aS1, aD1, as1, ad1, NNODES);
  k_agg<4,true><<<(NNODES+3)/4, 256, 0, stream>>>(hbuf, as1, ad1, offs, esrc, b1, out, NNODES);

  // layer 2
  k_gemm_mfma<256><<<gemm_grid, 256, 0, stream>>>(out, W2hi, W2lo, hbuf, NNODES);
  k_logits<1><<<(NNODES+3)/4, 256, 0, stream>>>(hbuf, aS2, aD2, as2, ad2, NNODES);
  k_agg<1,false><<<(NNODES+3)/4, 256, 0, stream>>>(hbuf, as2, ad2, offs, esrc, b2, out, NNODES);
}

// Round 3
// 503.220 us; speedup vs baseline: 1.4269x; 1.1044x over previous
//
#include <hip/hip_runtime.h>
#include <hip/hip_fp16.h>

#define NNODES 50000
#define NEDGES 800000
#define HIDDIM 256

constexpr float NEG = 0.2f;

typedef __attribute__((ext_vector_type(8))) short short8_t;   // bf16x8 MFMA frag
typedef __attribute__((ext_vector_type(4))) float floatx4;    // f32x4 acc

__device__ __forceinline__ float lrelu(float v){ return v >= 0.f ? v : NEG*v; }

__device__ __forceinline__ unsigned short bf16_rn(float x){
  unsigned u = __float_as_uint(x);
  return (unsigned short)((u + 0x7FFFu + ((u >> 16) & 1u)) >> 16);
}

// ---------------- CSR build (by dst, self-loops included) ----------------
__global__ void k_init_counts(int* counts, int n){
  int i = blockIdx.x*blockDim.x + threadIdx.x;
  if (i < n) counts[i] = 1;               // one self-loop per node
}
__global__ void k_count(const int* __restrict__ ei, int* counts, int E){
  int e = blockIdx.x*blockDim.x + threadIdx.x;
  if (e < E) atomicAdd(&counts[ei[E + e]], 1);   // dst row of edge_index
}
__global__ void k_scan(const int* __restrict__ counts, int* __restrict__ offs,
                       int* __restrict__ cursor, int n){
  __shared__ int sums[256];
  const int t = threadIdx.x;
  const int chunk = (n + 255)/256;
  const int lo = t*chunk, hi = min(n, lo+chunk);
  int s = 0;
  for (int i = lo; i < hi; ++i) s += counts[i];
  sums[t] = s;
  __syncthreads();
  if (t == 0){
    int run = 0;
    for (int i = 0; i < 256; ++i){ int v = sums[i]; sums[i] = run; run += v; }
    offs[n] = run;
  }
  __syncthreads();
  int run = sums[t];
  for (int i = lo; i < hi; ++i){ offs[i] = run; cursor[i] = run; run += counts[i]; }
}
__global__ void k_scatter(const int* __restrict__ ei, int* cursor,
                          int* __restrict__ esrc, int E, int n){
  int e = blockIdx.x*blockDim.x + threadIdx.x;
  if (e < E){
    int s = ei[e], d = ei[E+e];
    esrc[atomicAdd(&cursor[d], 1)] = s;
  } else if (e < E + n){
    int i = e - E;
    esrc[atomicAdd(&cursor[i], 1)] = i;    // self loop
  }
}

// ---------------- W split: fp32 -> bf16 hi/lo, fragment-permuted layout ----
__global__ void k_splitW(const float* __restrict__ W, unsigned short* __restrict__ hi,
                         unsigned short* __restrict__ lo, int K){
  int idx = blockIdx.x*256 + threadIdx.x;
  if (idx >= K*HIDDIM) return;
  int k = idx / HIDDIM, n = idx % HIDDIM;
  float w = W[idx];
  unsigned short h = bf16_rn(w);
  float hf = __uint_as_float((unsigned)h << 16);
  unsigned short l = bf16_rn(w - hf);
  int p = ((k >> 3)*HIDDIM + n)*8 + (k & 7);
  hi[p] = h; lo[p] = l;
}

// ---------------- MFMA GEMM + fused logits, fp16 h output --------------------
// BM=64, BN=256 (full N), 4 waves; wave w owns cols [64w,64w+64).
// split-bf16: D += Ahi*Bhi + Ahi*Blo + Alo*Bhi
template<int K, int NH>
__global__ __launch_bounds__(256) void k_gemm_mfma(
    const float* __restrict__ A,
    const unsigned short* __restrict__ Bhi, const unsigned short* __restrict__ Blo,
    const float* __restrict__ aS, const float* __restrict__ aD,
    __half* __restrict__ Hout, float* __restrict__ as_o, float* __restrict__ ad_o, int M)
{
  constexpr int LDSK = K + 8;
  __shared__ unsigned short sAhi[64*LDSK];
  __shared__ unsigned short sAlo[64*LDSK];
  __shared__ float lred_s[64][4], lred_d[64][4];
  const int tid = threadIdx.x;
  const int row0 = blockIdx.x*64;

  constexpr int CH = 64*K/4/256;
  #pragma unroll
  for (int c = 0; c < CH; ++c){
    const int chunk = c*256 + tid;
    const int r = chunk/(K/4), ko = (chunk%(K/4))*4;
    const int gr = min(row0 + r, M-1);
    const float4 v = *reinterpret_cast<const float4*>(A + (size_t)gr*K + ko);
    ushort4 h, l;
    h.x = bf16_rn(v.x); l.x = bf16_rn(v.x - __uint_as_float((unsigned)h.x<<16));
    h.y = bf16_rn(v.y); l.y = bf16_rn(v.y - __uint_as_float((unsigned)h.y<<16));
    h.z = bf16_rn(v.z); l.z = bf16_rn(v.z - __uint_as_float((unsigned)h.z<<16));
    h.w = bf16_rn(v.w); l.w = bf16_rn(v.w - __uint_as_float((unsigned)h.w<<16));
    *reinterpret_cast<ushort4*>(&sAhi[r*LDSK + ko]) = h;
    *reinterpret_cast<ushort4*>(&sAlo[r*LDSK + ko]) = l;
  }
  __syncthreads();

  const int w = tid >> 6, l = tid & 63;
  const int lr = l & 15, lg = l >> 4;
  const int n0 = w*64;
  floatx4 acc[4][4] = {};

  for (int ks = 0; ks < K/32; ++ks){
    short8_t ah[4], al[4], bh[4], bl[4];
    #pragma unroll
    for (int m = 0; m < 4; ++m){
      const int off = (16*m + lr)*LDSK + ks*32 + lg*8;
      ah[m] = *reinterpret_cast<const short8_t*>(&sAhi[off]);
      al[m] = *reinterpret_cast<const short8_t*>(&sAlo[off]);
    }
    #pragma unroll
    for (int n = 0; n < 4; ++n){
      const int boff = (((ks*4 + lg)*HIDDIM) + n0 + 16*n + lr)*8;
      bh[n] = *reinterpret_cast<const short8_t*>(&Bhi[boff]);
      bl[n] = *reinterpret_cast<const short8_t*>(&Blo[boff]);
    }
    #pragma unroll
    for (int m = 0; m < 4; ++m)
      #pragma unroll
      for (int n = 0; n < 4; ++n){
        acc[m][n] = __builtin_amdgcn_mfma_f32_16x16x32_bf16(ah[m], bh[n], acc[m][n], 0,0,0);
        acc[m][n] = __builtin_amdgcn_mfma_f32_16x16x32_bf16(ah[m], bl[n], acc[m][n], 0,0,0);
        acc[m][n] = __builtin_amdgcn_mfma_f32_16x16x32_bf16(al[m], bh[n], acc[m][n], 0,0,0);
      }
  }

  // ---- h store (fp16). D layout: col = lane&15 (+16n+n0), row = 4*lg + r (+16m)
  #pragma unroll
  for (int m = 0; m < 4; ++m){
    #pragma unroll
    for (int r = 0; r < 4; ++r){
      const int row = row0 + 16*m + lg*4 + r;
      if (row < M){
        #pragma unroll
        for (int n = 0; n < 4; ++n)
          Hout[(size_t)row*HIDDIM + n0 + 16*n + lr] = __float2half(acc[m][n][r]);
      }
    }
  }

  // ---- fused logits: as/ad[row] (per wave = 64 cols) from fp32 acc
  float asv[4], adv_[4];
  #pragma unroll
  for (int n = 0; n < 4; ++n){ asv[n] = aS[n0+16*n+lr]; adv_[n] = aD[n0+16*n+lr]; }
  #pragma unroll
  for (int m = 0; m < 4; ++m){
    #pragma unroll
    for (int r = 0; r < 4; ++r){
      float ps = 0.f, pd = 0.f;
      #pragma unroll
      for (int n = 0; n < 4; ++n){
        ps = fmaf(acc[m][n][r], asv[n], ps);
        pd = fmaf(acc[m][n][r], adv_[n], pd);
      }
      #pragma unroll
      for (int off = 1; off <= 8; off <<= 1){
        ps += __shfl_xor(ps, off);
        pd += __shfl_xor(pd, off);
      }
      const int rloc = 16*m + lg*4 + r;
      if (NH == 4){
        if (lr == 0 && row0 + rloc < M){
          as_o[(row0+rloc)*4 + w] = ps;
          ad_o[(row0+rloc)*4 + w] = pd;
        }
      } else {
        if (lr == 0){ lred_s[rloc][w] = ps; lred_d[rloc][w] = pd; }
      }
    }
  }
  if (NH == 1){
    __syncthreads();
    if (tid < 64 && row0 + tid < M){
      float a = lred_s[tid][0]+lred_s[tid][1]+lred_s[tid][2]+lred_s[tid][3];
      float b = lred_d[tid][0]+lred_d[tid][1]+lred_d[tid][2]+lred_d[tid][3];
      as_o[row0+tid] = a; ad_o[row0+tid] = b;
    }
  }
}

// ---------------- online softmax + aggregate; one wave per dst node ---------
template<int NH, bool DO_ELU>
__global__ __launch_bounds__(256) void k_agg(
    const __half* __restrict__ Hs,
    const float* __restrict__ as_, const float* __restrict__ ad_,
    const int* __restrict__ offs, const int* __restrict__ esrc,
    const float* __restrict__ bias, float* __restrict__ Out, int n)
{
  const int lane = threadIdx.x & 63;
  const int node = blockIdx.x*4 + (threadIdx.x >> 6);
  if (node >= n) return;
  const int start = offs[node], end = offs[node+1];

  float adv[NH], m[NH], dsum[NH];
  #pragma unroll
  for (int h = 0; h < NH; ++h){ adv[h] = ad_[node*NH + h]; m[h] = -1e30f; dsum[h] = 0.f; }

  // single pass: per-lane online max+denom
  for (int e = start + lane; e < end; e += 64){
    const int s = esrc[e];
    if (NH == 4){
      const float4 av = *reinterpret_cast<const float4*>(as_ + (size_t)s*4);
      const float a[4] = {av.x, av.y, av.z, av.w};
      #pragma unroll
      for (int h = 0; h < 4; ++h){
        const float v = lrelu(a[h] + adv[h]);
        const float mo = m[h], mn = fmaxf(mo, v);
        dsum[h] = dsum[h]*__expf(mo - mn) + __expf(v - mn);
        m[h] = mn;
      }
    } else {
      const float v = lrelu(as_[s] + adv[0]);
      const float mo = m[0], mn = fmaxf(mo, v);
      dsum[0] = dsum[0]*__expf(mo - mn) + __expf(v - mn);
      m[0] = mn;
    }
  }
  // cross-lane online merge
  #pragma unroll
  for (int h = 0; h < NH; ++h){
    for (int off = 32; off; off >>= 1){
      const float mo = __shfl_xor(m[h], off);
      const float dd = __shfl_xor(dsum[h], off);
      const float mn = fmaxf(m[h], mo);
      dsum[h] = dsum[h]*__expf(m[h] - mn) + dd*__expf(mo - mn);
      m[h] = mn;
    }
  }

  const int head = (NH == 4) ? (lane >> 4) : 0;
  float mh, adh, rdh;
  if (NH == 4){
    mh  = (head & 2) ? ((head & 1) ? m[3]   : m[2])   : ((head & 1) ? m[1]   : m[0]);
    adh = (head & 2) ? ((head & 1) ? adv[3] : adv[2]) : ((head & 1) ? adv[1] : adv[0]);
    const float ds = (head & 2) ? ((head & 1) ? dsum[3] : dsum[2]) : ((head & 1) ? dsum[1] : dsum[0]);
    rdh = 1.f/(ds + 1e-16f);
  } else {
    mh = m[0]; adh = adv[0]; rdh = 1.f/(dsum[0] + 1e-16f);
  }

  float4 acc = {0.f, 0.f, 0.f, 0.f};
  for (int e = start; e < end; ++e){
    const int s = esrc[e];                                   // wave-uniform
    const float av = as_[(size_t)s*NH + head];
    const float p = __expf(lrelu(av + adh) - mh) * rdh;
    union { float2 f; __half2 h[2]; } u;
    u.f = *reinterpret_cast<const float2*>(Hs + (size_t)s*HIDDIM + 4*lane);
    const float2 lo = __half22float2(u.h[0]);
    const float2 hi = __half22float2(u.h[1]);
    acc.x = fmaf(p, lo.x, acc.x);
    acc.y = fmaf(p, lo.y, acc.y);
    acc.z = fmaf(p, hi.x, acc.z);
    acc.w = fmaf(p, hi.y, acc.w);
  }
  const float4 bv = *reinterpret_cast<const float4*>(bias + 4*lane);
  acc.x += bv.x; acc.y += bv.y; acc.z += bv.z; acc.w += bv.w;
  if (DO_ELU){
    acc.x = acc.x > 0.f ? acc.x : __expf(acc.x) - 1.f;
    acc.y = acc.y > 0.f ? acc.y : __expf(acc.y) - 1.f;
    acc.z = acc.z > 0.f ? acc.z : __expf(acc.z) - 1.f;
    acc.w = acc.w > 0.f ? acc.w : __expf(acc.w) - 1.f;
  }
  *reinterpret_cast<float4*>(Out + (size_t)node*HIDDIM + 4*lane) = acc;
}

// ---------------- launch ----------------
extern "C" void kernel_launch(void* const* d_in, const int* in_sizes, int n_in,
                              void* d_out, int out_size, void* d_ws, size_t ws_size,
                              hipStream_t stream)
{
  const float* x    = (const float*)d_in[0];
  const int*   ei   = (const int*)  d_in[1];
  const float* W1   = (const float*)d_in[2];
  const float* aS1  = (const float*)d_in[3];
  const float* aD1  = (const float*)d_in[4];
  const float* b1   = (const float*)d_in[5];
  const float* W2   = (const float*)d_in[6];
  const float* aS2  = (const float*)d_in[7];
  const float* aD2  = (const float*)d_in[8];
  const float* b2   = (const float*)d_in[9];
  float* out = (float*)d_out;

  char* ws = (char*)d_ws;
  size_t off = 0;
  auto alloc = [&](size_t bytes){ void* p = ws + off; off += (bytes + 255) & ~255ull; return p; };
  __half* hbuf  = (__half*)alloc((size_t)NNODES*HIDDIM*sizeof(__half)); // 25.6 MB
  float* as1    = (float*)alloc((size_t)NNODES*4*sizeof(float));
  float* ad1    = (float*)alloc((size_t)NNODES*4*sizeof(float));
  float* as2    = (float*)alloc((size_t)NNODES*sizeof(float));
  float* ad2    = (float*)alloc((size_t)NNODES*sizeof(float));
  unsigned short* W1hi = (unsigned short*)alloc((size_t)128*HIDDIM*sizeof(short));
  unsigned short* W1lo = (unsigned short*)alloc((size_t)128*HIDDIM*sizeof(short));
  unsigned short* W2hi = (unsigned short*)alloc((size_t)256*HIDDIM*sizeof(short));
  unsigned short* W2lo = (unsigned short*)alloc((size_t)256*HIDDIM*sizeof(short));
  int*   counts = (int*)alloc((size_t)NNODES*sizeof(int));
  int*   offs   = (int*)alloc((size_t)(NNODES+1)*sizeof(int));
  int*   cursor = (int*)alloc((size_t)NNODES*sizeof(int));
  int*   esrc   = (int*)alloc((size_t)(NEDGES+NNODES)*sizeof(int));

  // CSR by dst
  k_init_counts<<<(NNODES+255)/256, 256, 0, stream>>>(counts, NNODES);
  k_count     <<<(NEDGES+255)/256, 256, 0, stream>>>(ei, counts, NEDGES);
  k_scan      <<<1, 256, 0, stream>>>(counts, offs, cursor, NNODES);
  k_scatter   <<<(NEDGES+NNODES+255)/256, 256, 0, stream>>>(ei, cursor, esrc, NEDGES, NNODES);

  // weight splits
  k_splitW<<<(128*HIDDIM+255)/256, 256, 0, stream>>>(W1, W1hi, W1lo, 128);
  k_splitW<<<(256*HIDDIM+255)/256, 256, 0, stream>>>(W2, W2hi, W2lo, 256);

  const int gemm_grid = (NNODES + 63)/64;   // 782

  // layer 1
  k_gemm_mfma<128,4><<<gemm_grid, 256, 0, stream>>>(x, W1hi, W1lo, aS1, aD1, hbuf, as1, ad1, NNODES);
  k_agg<4,true><<<(NNODES+3)/4, 256, 0, stream>>>(hbuf, as1, ad1, offs, esrc, b1, out, NNODES);

  // layer 2
  k_gemm_mfma<256,1><<<gemm_grid, 256, 0, stream>>>(out, W2hi, W2lo, aS2, aD2, hbuf, as2, ad2, NNODES);
  k_agg<1,false><<<(NNODES+3)/4, 256, 0, stream>>>(hbuf, as2, ad2, offs, esrc, b2, out, NNODES);
}

// Round 4
// 392.209 us; speedup vs baseline: 1.8308x; 1.2830x over previous
//
#include <hip/hip_runtime.h>
#include <hip/hip_fp16.h>

#define NNODES 50000
#define NEDGES 800000
#define HIDDIM 256

constexpr float NEG = 0.2f;

typedef __attribute__((ext_vector_type(8))) short short8_t;   // bf16x8 MFMA frag
typedef __attribute__((ext_vector_type(4))) float floatx4;    // f32x4 acc

__device__ __forceinline__ float lrelu(float v){ return v >= 0.f ? v : NEG*v; }

__device__ __forceinline__ unsigned short bf16_rn(float x){
  unsigned u = __float_as_uint(x);
  return (unsigned short)((u + 0x7FFFu + ((u >> 16) & 1u)) >> 16);
}

// ---------------- CSR build (by dst, self-loops included) ----------------
__global__ void k_init_counts(int* counts, int n){
  int i = blockIdx.x*blockDim.x + threadIdx.x;
  if (i < n) counts[i] = 1;               // one self-loop per node
}
__global__ void k_count(const int* __restrict__ ei, int* counts, int E){
  int e = blockIdx.x*blockDim.x + threadIdx.x;
  if (e < E) atomicAdd(&counts[ei[E + e]], 1);   // dst row of edge_index
}

// ---- hierarchical exclusive scan: 2048 elements per block ----
#define SCAN_CHUNK 2048
__global__ __launch_bounds__(256) void k_scan_a(const int* __restrict__ counts,
                                                int* __restrict__ bsum, int n){
  __shared__ int ws[4];
  const int t = threadIdx.x;
  const int idx0 = blockIdx.x*SCAN_CHUNK + t*8;
  int s = 0;
  #pragma unroll
  for (int i = 0; i < 8; ++i) if (idx0 + i < n) s += counts[idx0 + i];
  for (int off = 32; off; off >>= 1) s += __shfl_xor(s, off);
  if ((t & 63) == 0) ws[t >> 6] = s;
  __syncthreads();
  if (t == 0) bsum[blockIdx.x] = ws[0] + ws[1] + ws[2] + ws[3];
}
__global__ void k_scan_b(const int* __restrict__ bsum, int* __restrict__ boff,
                         int* __restrict__ offs, int nb, int n){
  if (threadIdx.x == 0){
    int run = 0;
    for (int i = 0; i < nb; ++i){ boff[i] = run; run += bsum[i]; }
    offs[n] = run;                         // total = NEDGES + NNODES
  }
}
__global__ __launch_bounds__(256) void k_scan_c(const int* __restrict__ counts,
                                                const int* __restrict__ boff,
                                                int* __restrict__ offs,
                                                int* __restrict__ cursor, int n){
  __shared__ int sc[256];
  const int t = threadIdx.x;
  const int idx0 = blockIdx.x*SCAN_CHUNK + t*8;
  int v[8], pre[8], s = 0;
  #pragma unroll
  for (int i = 0; i < 8; ++i){
    v[i] = (idx0 + i < n) ? counts[idx0 + i] : 0;
    pre[i] = s; s += v[i];
  }
  sc[t] = s;
  __syncthreads();
  int run = s;
  for (int off = 1; off < 256; off <<= 1){
    int add = (t >= off) ? sc[t - off] : 0;
    __syncthreads();
    sc[t] += add;
    __syncthreads();
  }
  const int excl = sc[t] - run;
  const int toff = boff[blockIdx.x] + excl;
  #pragma unroll
  for (int i = 0; i < 8; ++i){
    if (idx0 + i < n){
      const int o = toff + pre[i];
      offs[idx0 + i] = o;
      cursor[idx0 + i] = o;
    }
  }
}

__global__ void k_scatter(const int* __restrict__ ei, int* cursor,
                          int* __restrict__ esrc, int E, int n){
  int e = blockIdx.x*blockDim.x + threadIdx.x;
  if (e < E){
    int s = ei[e], d = ei[E+e];
    esrc[atomicAdd(&cursor[d], 1)] = s;
  } else if (e < E + n){
    int i = e - E;
    esrc[atomicAdd(&cursor[i], 1)] = i;    // self loop
  }
}

// ---------------- W split: fp32 -> bf16 hi/lo, fragment-permuted layout ----
__global__ void k_splitW(const float* __restrict__ W, unsigned short* __restrict__ hi,
                         unsigned short* __restrict__ lo, int K){
  int idx = blockIdx.x*256 + threadIdx.x;
  if (idx >= K*HIDDIM) return;
  int k = idx / HIDDIM, n = idx % HIDDIM;
  float w = W[idx];
  unsigned short h = bf16_rn(w);
  float hf = __uint_as_float((unsigned)h << 16);
  unsigned short l = bf16_rn(w - hf);
  int p = ((k >> 3)*HIDDIM + n)*8 + (k & 7);
  hi[p] = h; lo[p] = l;
}

// ---------------- MFMA GEMM + fused logits, fp16 h output --------------------
template<int K, int NH>
__global__ __launch_bounds__(256) void k_gemm_mfma(
    const float* __restrict__ A,
    const unsigned short* __restrict__ Bhi, const unsigned short* __restrict__ Blo,
    const float* __restrict__ aS, const float* __restrict__ aD,
    __half* __restrict__ Hout, float* __restrict__ as_o, float* __restrict__ ad_o, int M)
{
  constexpr int LDSK = K + 8;
  __shared__ unsigned short sAhi[64*LDSK];
  __shared__ unsigned short sAlo[64*LDSK];
  __shared__ float lred_s[64][4], lred_d[64][4];
  const int tid = threadIdx.x;
  const int row0 = blockIdx.x*64;

  constexpr int CH = 64*K/4/256;
  #pragma unroll
  for (int c = 0; c < CH; ++c){
    const int chunk = c*256 + tid;
    const int r = chunk/(K/4), ko = (chunk%(K/4))*4;
    const int gr = min(row0 + r, M-1);
    const float4 v = *reinterpret_cast<const float4*>(A + (size_t)gr*K + ko);
    ushort4 h, l;
    h.x = bf16_rn(v.x); l.x = bf16_rn(v.x - __uint_as_float((unsigned)h.x<<16));
    h.y = bf16_rn(v.y); l.y = bf16_rn(v.y - __uint_as_float((unsigned)h.y<<16));
    h.z = bf16_rn(v.z); l.z = bf16_rn(v.z - __uint_as_float((unsigned)h.z<<16));
    h.w = bf16_rn(v.w); l.w = bf16_rn(v.w - __uint_as_float((unsigned)h.w<<16));
    *reinterpret_cast<ushort4*>(&sAhi[r*LDSK + ko]) = h;
    *reinterpret_cast<ushort4*>(&sAlo[r*LDSK + ko]) = l;
  }
  __syncthreads();

  const int w = tid >> 6, l = tid & 63;
  const int lr = l & 15, lg = l >> 4;
  const int n0 = w*64;
  floatx4 acc[4][4] = {};

  for (int ks = 0; ks < K/32; ++ks){
    short8_t ah[4], al[4], bh[4], bl[4];
    #pragma unroll
    for (int m = 0; m < 4; ++m){
      const int off = (16*m + lr)*LDSK + ks*32 + lg*8;
      ah[m] = *reinterpret_cast<const short8_t*>(&sAhi[off]);
      al[m] = *reinterpret_cast<const short8_t*>(&sAlo[off]);
    }
    #pragma unroll
    for (int n = 0; n < 4; ++n){
      const int boff = (((ks*4 + lg)*HIDDIM) + n0 + 16*n + lr)*8;
      bh[n] = *reinterpret_cast<const short8_t*>(&Bhi[boff]);
      bl[n] = *reinterpret_cast<const short8_t*>(&Blo[boff]);
    }
    #pragma unroll
    for (int m = 0; m < 4; ++m)
      #pragma unroll
      for (int n = 0; n < 4; ++n){
        acc[m][n] = __builtin_amdgcn_mfma_f32_16x16x32_bf16(ah[m], bh[n], acc[m][n], 0,0,0);
        acc[m][n] = __builtin_amdgcn_mfma_f32_16x16x32_bf16(ah[m], bl[n], acc[m][n], 0,0,0);
        acc[m][n] = __builtin_amdgcn_mfma_f32_16x16x32_bf16(al[m], bh[n], acc[m][n], 0,0,0);
      }
  }

  #pragma unroll
  for (int m = 0; m < 4; ++m){
    #pragma unroll
    for (int r = 0; r < 4; ++r){
      const int row = row0 + 16*m + lg*4 + r;
      if (row < M){
        #pragma unroll
        for (int n = 0; n < 4; ++n)
          Hout[(size_t)row*HIDDIM + n0 + 16*n + lr] = __float2half(acc[m][n][r]);
      }
    }
  }

  float asv[4], adv_[4];
  #pragma unroll
  for (int n = 0; n < 4; ++n){ asv[n] = aS[n0+16*n+lr]; adv_[n] = aD[n0+16*n+lr]; }
  #pragma unroll
  for (int m = 0; m < 4; ++m){
    #pragma unroll
    for (int r = 0; r < 4; ++r){
      float ps = 0.f, pd = 0.f;
      #pragma unroll
      for (int n = 0; n < 4; ++n){
        ps = fmaf(acc[m][n][r], asv[n], ps);
        pd = fmaf(acc[m][n][r], adv_[n], pd);
      }
      #pragma unroll
      for (int off = 1; off <= 8; off <<= 1){
        ps += __shfl_xor(ps, off);
        pd += __shfl_xor(pd, off);
      }
      const int rloc = 16*m + lg*4 + r;
      if (NH == 4){
        if (lr == 0 && row0 + rloc < M){
          as_o[(row0+rloc)*4 + w] = ps;
          ad_o[(row0+rloc)*4 + w] = pd;
        }
      } else {
        if (lr == 0){ lred_s[rloc][w] = ps; lred_d[rloc][w] = pd; }
      }
    }
  }
  if (NH == 1){
    __syncthreads();
    if (tid < 64 && row0 + tid < M){
      float a = lred_s[tid][0]+lred_s[tid][1]+lred_s[tid][2]+lred_s[tid][3];
      float b = lred_d[tid][0]+lred_d[tid][1]+lred_d[tid][2]+lred_d[tid][3];
      as_o[row0+tid] = a; ad_o[row0+tid] = b;
    }
  }
}

// ---------------- online softmax + aggregate; one wave per dst node ---------
template<int NH, bool DO_ELU>
__global__ __launch_bounds__(256) void k_agg(
    const __half* __restrict__ Hs,
    const float* __restrict__ as_, const float* __restrict__ ad_,
    const int* __restrict__ offs, const int* __restrict__ esrc,
    const float* __restrict__ bias, float* __restrict__ Out, int n)
{
  const int lane = threadIdx.x & 63;
  const int node = blockIdx.x*4 + (threadIdx.x >> 6);
  if (node >= n) return;
  const int start = offs[node], end = offs[node+1];

  float adv[NH], m[NH], dsum[NH];
  #pragma unroll
  for (int h = 0; h < NH; ++h){ adv[h] = ad_[node*NH + h]; m[h] = -1e30f; dsum[h] = 0.f; }

  for (int e = start + lane; e < end; e += 64){
    const int s = esrc[e];
    if (NH == 4){
      const float4 av = *reinterpret_cast<const float4*>(as_ + (size_t)s*4);
      const float a[4] = {av.x, av.y, av.z, av.w};
      #pragma unroll
      for (int h = 0; h < 4; ++h){
        const float v = lrelu(a[h] + adv[h]);
        const float mo = m[h], mn = fmaxf(mo, v);
        dsum[h] = dsum[h]*__expf(mo - mn) + __expf(v - mn);
        m[h] = mn;
      }
    } else {
      const float v = lrelu(as_[s] + adv[0]);
      const float mo = m[0], mn = fmaxf(mo, v);
      dsum[0] = dsum[0]*__expf(mo - mn) + __expf(v - mn);
      m[0] = mn;
    }
  }
  #pragma unroll
  for (int h = 0; h < NH; ++h){
    for (int off = 32; off; off >>= 1){
      const float mo = __shfl_xor(m[h], off);
      const float dd = __shfl_xor(dsum[h], off);
      const float mn = fmaxf(m[h], mo);
      dsum[h] = dsum[h]*__expf(m[h] - mn) + dd*__expf(mo - mn);
      m[h] = mn;
    }
  }

  const int head = (NH == 4) ? (lane >> 4) : 0;
  float mh, adh, rdh;
  if (NH == 4){
    mh  = (head & 2) ? ((head & 1) ? m[3]   : m[2])   : ((head & 1) ? m[1]   : m[0]);
    adh = (head & 2) ? ((head & 1) ? adv[3] : adv[2]) : ((head & 1) ? adv[1] : adv[0]);
    const float ds = (head & 2) ? ((head & 1) ? dsum[3] : dsum[2]) : ((head & 1) ? dsum[1] : dsum[0]);
    rdh = 1.f/(ds + 1e-16f);
  } else {
    mh = m[0]; adh = adv[0]; rdh = 1.f/(dsum[0] + 1e-16f);
  }

  float4 acc = {0.f, 0.f, 0.f, 0.f};
  for (int e = start; e < end; ++e){
    const int s = esrc[e];                                   // wave-uniform
    const float av = as_[(size_t)s*NH + head];
    const float p = __expf(lrelu(av + adh) - mh) * rdh;
    union { float2 f; __half2 h[2]; } u;
    u.f = *reinterpret_cast<const float2*>(Hs + (size_t)s*HIDDIM + 4*lane);
    const float2 lo = __half22float2(u.h[0]);
    const float2 hi = __half22float2(u.h[1]);
    acc.x = fmaf(p, lo.x, acc.x);
    acc.y = fmaf(p, lo.y, acc.y);
    acc.z = fmaf(p, hi.x, acc.z);
    acc.w = fmaf(p, hi.y, acc.w);
  }
  const float4 bv = *reinterpret_cast<const float4*>(bias + 4*lane);
  acc.x += bv.x; acc.y += bv.y; acc.z += bv.z; acc.w += bv.w;
  if (DO_ELU){
    acc.x = acc.x > 0.f ? acc.x : __expf(acc.x) - 1.f;
    acc.y = acc.y > 0.f ? acc.y : __expf(acc.y) - 1.f;
    acc.z = acc.z > 0.f ? acc.z : __expf(acc.z) - 1.f;
    acc.w = acc.w > 0.f ? acc.w : __expf(acc.w) - 1.f;
  }
  *reinterpret_cast<float4*>(Out + (size_t)node*HIDDIM + 4*lane) = acc;
}

// ---------------- launch ----------------
extern "C" void kernel_launch(void* const* d_in, const int* in_sizes, int n_in,
                              void* d_out, int out_size, void* d_ws, size_t ws_size,
                              hipStream_t stream)
{
  const float* x    = (const float*)d_in[0];
  const int*   ei   = (const int*)  d_in[1];
  const float* W1   = (const float*)d_in[2];
  const float* aS1  = (const float*)d_in[3];
  const float* aD1  = (const float*)d_in[4];
  const float* b1   = (const float*)d_in[5];
  const float* W2   = (const float*)d_in[6];
  const float* aS2  = (const float*)d_in[7];
  const float* aD2  = (const float*)d_in[8];
  const float* b2   = (const float*)d_in[9];
  float* out = (float*)d_out;

  char* ws = (char*)d_ws;
  size_t off = 0;
  auto alloc = [&](size_t bytes){ void* p = ws + off; off += (bytes + 255) & ~255ull; return p; };
  __half* hbuf  = (__half*)alloc((size_t)NNODES*HIDDIM*sizeof(__half)); // 25.6 MB
  float* as1    = (float*)alloc((size_t)NNODES*4*sizeof(float));
  float* ad1    = (float*)alloc((size_t)NNODES*4*sizeof(float));
  float* as2    = (float*)alloc((size_t)NNODES*sizeof(float));
  float* ad2    = (float*)alloc((size_t)NNODES*sizeof(float));
  unsigned short* W1hi = (unsigned short*)alloc((size_t)128*HIDDIM*sizeof(short));
  unsigned short* W1lo = (unsigned short*)alloc((size_t)128*HIDDIM*sizeof(short));
  unsigned short* W2hi = (unsigned short*)alloc((size_t)256*HIDDIM*sizeof(short));
  unsigned short* W2lo = (unsigned short*)alloc((size_t)256*HIDDIM*sizeof(short));
  int*   counts = (int*)alloc((size_t)NNODES*sizeof(int));
  int*   offs   = (int*)alloc((size_t)(NNODES+1)*sizeof(int));
  int*   cursor = (int*)alloc((size_t)NNODES*sizeof(int));
  int*   bsum   = (int*)alloc(64*sizeof(int));
  int*   boff   = (int*)alloc(64*sizeof(int));
  int*   esrc   = (int*)alloc((size_t)(NEDGES+NNODES)*sizeof(int));

  const int nscan = (NNODES + SCAN_CHUNK - 1)/SCAN_CHUNK;   // 25

  // CSR by dst
  k_init_counts<<<(NNODES+255)/256, 256, 0, stream>>>(counts, NNODES);
  k_count     <<<(NEDGES+255)/256, 256, 0, stream>>>(ei, counts, NEDGES);
  k_scan_a    <<<nscan, 256, 0, stream>>>(counts, bsum, NNODES);
  k_scan_b    <<<1, 64, 0, stream>>>(bsum, boff, offs, nscan, NNODES);
  k_scan_c    <<<nscan, 256, 0, stream>>>(counts, boff, offs, cursor, NNODES);
  k_scatter   <<<(NEDGES+NNODES+255)/256, 256, 0, stream>>>(ei, cursor, esrc, NEDGES, NNODES);

  // weight splits
  k_splitW<<<(128*HIDDIM+255)/256, 256, 0, stream>>>(W1, W1hi, W1lo, 128);
  k_splitW<<<(256*HIDDIM+255)/256, 256, 0, stream>>>(W2, W2hi, W2lo, 256);

  const int gemm_grid = (NNODES + 63)/64;   // 782

  // layer 1
  k_gemm_mfma<128,4><<<gemm_grid, 256, 0, stream>>>(x, W1hi, W1lo, aS1, aD1, hbuf, as1, ad1, NNODES);
  k_agg<4,true><<<(NNODES+3)/4, 256, 0, stream>>>(hbuf, as1, ad1, offs, esrc, b1, out, NNODES);

  // layer 2
  k_gemm_mfma<256,1><<<gemm_grid, 256, 0, stream>>>(out, W2hi, W2lo, aS2, aD2, hbuf, as2, ad2, NNODES);
  k_agg<1,false><<<(NNODES+3)/4, 256, 0, stream>>>(hbuf, as2, ad2, offs, esrc, b2, out, NNODES);
}